// Round 3
// baseline (4170.383 us; speedup 1.0000x reference)
//
#include <hip/hip_runtime.h>

// SSMTrack: B=8, S=4096, H=1024, D=256
//   inp = x @ W_in + b_in                        (bf16 MFMA GEMM)
//   s_t = tanh(inp_t + s_{t-1} @ W_state + b_s)  (MFMA scan: replicated-A rows,
//                                                 W in VGPR B-frags, 2 waves/CU)
//   out = states @ W_out + b_out                 (bf16 MFMA GEMM)

typedef float v4f __attribute__((ext_vector_type(4)));
typedef __bf16 bf16x4 __attribute__((ext_vector_type(4)));
typedef __bf16 bf16x8 __attribute__((ext_vector_type(8)));

#define BARRIER_LGKM() asm volatile("s_waitcnt lgkmcnt(0)\n\ts_barrier" ::: "memory")

// ---------------------------------------------------------------- conversions
__global__ void cvt_f32_bf16_x4(const float* __restrict__ in,
                                __bf16* __restrict__ out, int n4) {
  int i = blockIdx.x * blockDim.x + threadIdx.x;
  if (i >= n4) return;
  v4f v = ((const v4f*)in)[i];
  bf16x4 o;
  o.x = (__bf16)v.x; o.y = (__bf16)v.y; o.z = (__bf16)v.z; o.w = (__bf16)v.w;
  ((bf16x4*)out)[i] = o;
}

// in: [K,N] f32 row-major  ->  out: [N,K] bf16 row-major (i.e. B^T)
__global__ void transpose_cvt(const float* __restrict__ in,
                              __bf16* __restrict__ out, int K, int N) {
  int i = blockIdx.x * blockDim.x + threadIdx.x;
  if (i >= K * N) return;
  int k = i / N;
  int n = i - k * N;
  out[(size_t)n * K + k] = (__bf16)in[i];
}

// W_state[256][256] f32 -> B-fragment-swizzled bf16:
// Wswz[(kstep*16 + nt)*64 + lane][j] = W[32*kstep + (lane>>4)*8 + j][nt*16 + (lane&15)]
__global__ void prep_wswz(const float* __restrict__ W, __bf16* __restrict__ out) {
  int id = blockIdx.x * blockDim.x + threadIdx.x;  // 0..8191
  if (id >= 8192) return;
  int lane = id & 63;
  int frag = id >> 6;
  int nt = frag & 15;
  int kstep = frag >> 4;
  int q = lane >> 4, r = lane & 15;
  bf16x8 v;
#pragma unroll
  for (int j = 0; j < 8; ++j) {
    int k = 32 * kstep + q * 8 + j;
    v[j] = (__bf16)W[(size_t)k * 256 + nt * 16 + r];
  }
  ((bf16x8*)out)[id] = v;
}

// ---------------------------------------------------------------- GEMM (bf16)
// C[M,N] (f32) = A[M,K](bf16) * B, Bt[N,K] = B^T (bf16). One wave / 16x16 tile.
// C/D: col = l&15, row = (l>>4)*4 + i   (m89-verified)
__global__ void gemm_bt(const __bf16* __restrict__ A,
                        const __bf16* __restrict__ Bt,
                        const float* __restrict__ bias,
                        float* __restrict__ C,
                        int M, int N, int K) {
  int wid  = (blockIdx.x * blockDim.x + threadIdx.x) >> 6;
  int lane = threadIdx.x & 63;
  int ntiles = N >> 4;
  int mt = wid / ntiles;
  int nt = wid - mt * ntiles;
  if (mt * 16 >= M) return;
  int r = lane & 15;
  int q = lane >> 4;
  const __bf16* arow = A + (size_t)(mt * 16 + r) * K + q * 8;
  const __bf16* brow = Bt + (size_t)(nt * 16 + r) * K + q * 8;
  v4f acc = {0.f, 0.f, 0.f, 0.f};
  for (int k = 0; k < K; k += 32) {
    bf16x8 af = *(const bf16x8*)(arow + k);
    bf16x8 bf = *(const bf16x8*)(brow + k);
    acc = __builtin_amdgcn_mfma_f32_16x16x32_bf16(af, bf, acc, 0, 0, 0);
  }
  int col = nt * 16 + r;
  float bv = bias[col];
  size_t base = (size_t)(mt * 16 + q * 4) * N + col;
#pragma unroll
  for (int i = 0; i < 4; ++i) C[base + (size_t)i * N] = acc[i] + bv;
}

// ---------------------------------------------------------------- scan (MFMA)
// One block of 128 threads (2 waves) per batch. Wave w owns output cols
// [128w, 128w+128) = 8 N-tiles. W_state lives in VGPRs as 64 B-fragments
// (preloaded from Wswz). A rows are replicated with the state vector
// (A[m][k] = s[k]), so C rows are all identical and every quad holds every
// column's dot product -> epilogue is spread across all 4 quads (2 cols/lane).
// State ping-pongs between two 512 B LDS buffers; ONE raw barrier per step
// (lgkm-only wait keeps u-prefetch loads and bf16 global stores in flight).
// LDS pipe/step: 16x ds_read_b128 + 4x ds_write_b16 (~210 cy) overlapped with
// 64 MFMA/SIMD (~307 cy).
__global__ __launch_bounds__(128, 1) void scan_mfma(
    const float* __restrict__ inp,      // [B*S, 256] f32
    const __bf16* __restrict__ Wswz,    // [8*16*64] bf16x8 fragments
    const float* __restrict__ b_state,  // [256] f32
    __bf16* __restrict__ states,        // [B*S, 256] bf16 (out)
    int S) {
  const int tid = threadIdx.x;
  const int wv = tid >> 6;        // 0,1
  const int lane = tid & 63;
  const int quad = lane >> 4;     // 0..3
  const int r = lane & 15;
  const int b = blockIdx.x;

  __shared__ __align__(16) __bf16 sbuf[2][256];

  // Preload B-frags: Bf[kstep][i] for tiles nt = 8*wv + i.  256 VGPRs.
  bf16x8 Bf[8][8];
#pragma unroll
  for (int k = 0; k < 8; ++k)
#pragma unroll
    for (int i = 0; i < 8; ++i)
      Bf[k][i] = ((const bf16x8*)Wswz)[((k * 16) + (8 * wv + i)) * 64 + lane];

  const int col0 = 128 * wv + 32 * quad + r;  // tile i0 = 2*quad
  const int col1 = col0 + 16;                 // tile i1 = 2*quad+1
  const float bst0 = b_state[col0];
  const float bst1 = b_state[col1];
  const float* inpb = inp + (size_t)b * S * 256;
  __bf16* stb = states + (size_t)b * S * 256;

  sbuf[0][tid] = (__bf16)0.f;
  sbuf[0][tid + 128] = (__bf16)0.f;
  float u0 = inpb[col0];  // u for t=0
  float u1 = inpb[col1];
  __syncthreads();

  int cur = 0;
  for (int t = 0; t < S; ++t) {
    // A-fragments: lane reads s[quad*8 + 32k .. +8) -- 8x ds_read_b128,
    // 16 B unique per quad (4-way same-address groups, conflict-free).
    const __bf16* sp = sbuf[cur];
    bf16x8 Af[8];
#pragma unroll
    for (int k = 0; k < 8; ++k)
      Af[k] = *(const bf16x8*)(sp + quad * 8 + 32 * k);

    // prefetch next step's u while MFMAs run
    int t1 = (t + 1 < S) ? t + 1 : t;
    float n0 = inpb[(size_t)t1 * 256 + col0];
    float n1 = inpb[(size_t)t1 * 256 + col1];

    v4f acc[8];
#pragma unroll
    for (int i = 0; i < 8; ++i) acc[i] = (v4f){0.f, 0.f, 0.f, 0.f};
#pragma unroll
    for (int k = 0; k < 8; ++k)
#pragma unroll
      for (int i = 0; i < 8; ++i)
        acc[i] = __builtin_amdgcn_mfma_f32_16x16x32_bf16(Af[k], Bf[k][i], acc[i], 0, 0, 0);

    // rows are replicated -> reg 0 of tile 2*quad(+1) is this lane's col value
    float a0 = (quad < 2) ? ((quad == 0) ? acc[0][0] : acc[2][0])
                          : ((quad == 2) ? acc[4][0] : acc[6][0]);
    float a1 = (quad < 2) ? ((quad == 0) ? acc[1][0] : acc[3][0])
                          : ((quad == 2) ? acc[5][0] : acc[7][0]);
    float x0 = a0 + u0 + bst0;
    float x1 = a1 + u1 + bst1;
    // tanh(x) = 1 - 2/(exp(2x)+1); saturates correctly at +/-inf
    float s0 = 1.f - 2.f * __builtin_amdgcn_rcpf(__expf(2.f * x0) + 1.f);
    float s1 = 1.f - 2.f * __builtin_amdgcn_rcpf(__expf(2.f * x1) + 1.f);

    int nxt = cur ^ 1;
    sbuf[nxt][col0] = (__bf16)s0;
    sbuf[nxt][col1] = (__bf16)s1;
    stb[(size_t)t * 256 + col0] = (__bf16)s0;  // fire-and-forget
    stb[(size_t)t * 256 + col1] = (__bf16)s1;
    u0 = n0; u1 = n1;
    cur = nxt;
    BARRIER_LGKM();
  }
}

// ---------------------------------------------------------------- launch
extern "C" void kernel_launch(void* const* d_in, const int* in_sizes, int n_in,
                              void* d_out, int out_size, void* d_ws,
                              size_t ws_size, hipStream_t stream) {
  const float* x       = (const float*)d_in[0];  // [8,4096,1024]
  const float* W_in    = (const float*)d_in[1];  // [1024,256]
  const float* b_in    = (const float*)d_in[2];  // [256]
  const float* W_state = (const float*)d_in[3];  // [256,256]
  const float* b_state = (const float*)d_in[4];  // [256]
  const float* W_out   = (const float*)d_in[5];  // [256,1024]
  const float* b_out   = (const float*)d_in[6];  // [1024]
  float* out = (float*)d_out;                    // [8,4096,1024]

  const int B = 8, S = 4096, H = 1024, D = 256;
  const int M = B * S;  // 32768

  char* ws = (char*)d_ws;
  float*  inp    = (float*)(ws + 0);            // 32 MB  [M,D] f32
  __bf16* states = (__bf16*)(ws + 33554432);    // 16 MB  [M,D] bf16
  __bf16* xb     = (__bf16*)(ws + 50331648);    // 64 MB  [M,H] bf16
  __bf16* WinT   = (__bf16*)(ws + 117440512);   // 0.5 MB [D,H] bf16  (W_in^T)
  __bf16* WoutT  = (__bf16*)(ws + 117964800);   // 0.5 MB [H,D] bf16  (W_out^T)
  // Wswz aliases the start of xb -- written only AFTER phase-1 GEMM is done.
  __bf16* Wswz   = (__bf16*)(ws + 50331648);    // 128 KB swizzled W_state

  // conversions
  cvt_f32_bf16_x4<<<(M * H / 4 + 255) / 256, 256, 0, stream>>>(x, xb, M * H / 4);
  transpose_cvt<<<(H * D + 255) / 256, 256, 0, stream>>>(W_in, WinT, H, D);
  transpose_cvt<<<(D * H + 255) / 256, 256, 0, stream>>>(W_out, WoutT, D, H);

  // phase 1: inp = x @ W_in + b_in   (M=32768, N=256, K=1024)
  {
    int waves = (M / 16) * (D / 16);
    gemm_bt<<<waves / 4, 256, 0, stream>>>(xb, WinT, b_in, inp, M, D, H);
  }

  // W_state -> B-fragment swizzle (xb is dead now)
  prep_wswz<<<8192 / 256, 256, 0, stream>>>(W_state, Wswz);

  // phase 2: sequential scan, one block (2 waves) per batch
  scan_mfma<<<B, 128, 0, stream>>>(inp, Wswz, b_state, states, S);

  // phase 3: out = states @ W_out + b_out   (M=32768, N=1024, K=256)
  {
    int waves = (M / 16) * (H / 16);
    gemm_bt<<<waves / 4, 256, 0, stream>>>(states, WoutT, b_out, out, M, H, D);
  }
}